// Round 13
// baseline (327.671 us; speedup 1.0000x reference)
//
#include <hip/hip_runtime.h>
#include <math.h>

typedef __attribute__((ext_vector_type(8))) short  bf16x8;
typedef __attribute__((ext_vector_type(8))) unsigned short u16x8;
typedef __attribute__((ext_vector_type(4))) float  f32x4;

#define MTOT 16384   // B*H*W

__device__ __forceinline__ float b2f(unsigned short h) {
  return __uint_as_float(((unsigned int)h) << 16);
}
__device__ __forceinline__ unsigned short f2bf(float f) {
  unsigned int u = __float_as_uint(f);
  unsigned int r = (u + 0x7fffu + ((u >> 16) & 1u)) >> 16;
  return (unsigned short)r;
}
__device__ __forceinline__ void gload16(const unsigned short* g, unsigned short* l) {
  __builtin_amdgcn_global_load_lds(
      (const __attribute__((address_space(1))) void*)g,
      (__attribute__((address_space(3))) void*)l, 16, 0, 0);
}

// ------- NCHW fp32 -> chunked bf16 planes  out[c4][m][64]  (m = b*4096 + y*64 + x) -------
__global__ __launch_bounds__(256) void nhwc_kernel(const float* __restrict__ in,
                                                   unsigned short* __restrict__ out) {
  const int y = blockIdx.x, b = blockIdx.y;
  const int t = threadIdx.x;
  __shared__ float lds[64 * 65];
  for (int c0 = 0; c0 < 256; c0 += 64) {
    #pragma unroll
    for (int i = 0; i < 16; ++i) {
      int cl = i * 4 + (t >> 6);
      int xx = t & 63;
      lds[cl * 65 + xx] = in[(((size_t)b * 256 + c0 + cl) * 64 + y) * 64 + xx];
    }
    __syncthreads();
    const int plane = c0 >> 6;
    #pragma unroll
    for (int i = 0; i < 16; ++i) {
      int xx = i * 4 + (t >> 6);
      int cl = t & 63;
      int m  = (b << 12) + (y << 6) + xx;
      out[((size_t)plane * MTOT + m) * 64 + cl] = f2bf(lds[cl * 65 + xx]);
    }
    __syncthreads();
  }
}

// ------- weight reorder: w[co][ci][kk] fp32 -> Wp[(kk*4+c4)*NPAD + co][64ci] bf16 -------
__global__ __launch_bounds__(256) void wprep_kernel(const float* __restrict__ w,
                                                    unsigned short* __restrict__ Wp,
                                                    int NPAD, int COUT_valid) {
  const int kkc4 = blockIdx.x;             // 0..35
  const int kk = kkc4 >> 2, c4 = kkc4 & 3;
  const int co = blockIdx.y * 4 + (threadIdx.x >> 6);
  const int c16 = threadIdx.x & 63;
  float v = (co < COUT_valid) ? w[((size_t)co * 256 + c4 * 64 + c16) * 9 + kk] : 0.0f;
  Wp[((size_t)kkc4 * NPAD + co) * 64 + c16] = f2bf(v);
}

// ------- bilinear sampler: t3 ([m][432] f32) + xh (chunked) -> S[s-plane][m][64] bf16 -------
__global__ __launch_bounds__(256) void sampler_kernel(const float* __restrict__ t3,
                                                      const unsigned short* __restrict__ xh,
                                                      unsigned short* __restrict__ S) {
  const int t = threadIdx.x;
  const int g = t & 15;
  const int m = blockIdx.x * 16 + (t >> 4);
  const int b = m >> 12, pix = m & 4095, y = pix >> 6, x = pix & 63;
  const float* off = t3 + (size_t)m * 432;
  const size_t gbase = ((size_t)(g >> 2) * MTOT + ((size_t)b << 12)) * 64 + (g & 3) * 16;

  #pragma unroll
  for (int kk = 0; kk < 9; ++kk) {
    const int ki = kk / 3, kj = kk % 3;
    float dyv = off[2 * (g * 9 + kk)];
    float dxv = off[2 * (g * 9 + kk) + 1];
    float ml  = off[288 + g * 9 + kk];
    float mk  = 1.0f / (1.0f + __expf(-ml));
    float ysf = (float)(y - 1 + ki) + dyv;
    float xsf = (float)(x - 1 + kj) + dxv;
    float y0f = floorf(ysf), x0f = floorf(xsf);
    float wy = ysf - y0f, wx = xsf - x0f;
    int yi0 = (int)y0f, xi0 = (int)x0f;
    int yi1 = yi0 + 1, xi1 = xi0 + 1;
    bool vy0 = (yi0 >= 0) && (yi0 < 64), vy1 = (yi1 >= 0) && (yi1 < 64);
    bool vx0 = (xi0 >= 0) && (xi0 < 64), vx1 = (xi1 >= 0) && (xi1 < 64);
    int yc0 = min(max(yi0, 0), 63), yc1 = min(max(yi1, 0), 63);
    int xc0 = min(max(xi0, 0), 63), xc1 = min(max(xi1, 0), 63);
    float w00 = (vy0 && vx0) ? (1.f - wy) * (1.f - wx) * mk : 0.f;
    float w01 = (vy0 && vx1) ? (1.f - wy) * wx * mk : 0.f;
    float w10 = (vy1 && vx0) ? wy * (1.f - wx) * mk : 0.f;
    float w11 = (vy1 && vx1) ? wy * wx * mk : 0.f;

    float sacc[16];
    #pragma unroll
    for (int c = 0; c < 16; ++c) sacc[c] = 0.f;

    const int p00 = yc0 * 64 + xc0, p01 = yc0 * 64 + xc1;
    const int p10 = yc1 * 64 + xc0, p11 = yc1 * 64 + xc1;
    {
      u16x8 lo = *(const u16x8*)(xh + gbase + (size_t)p00 * 64);
      u16x8 hi = *(const u16x8*)(xh + gbase + (size_t)p00 * 64 + 8);
      #pragma unroll
      for (int j = 0; j < 8; ++j) { sacc[j] += w00 * b2f(lo[j]); sacc[8 + j] += w00 * b2f(hi[j]); }
    }
    {
      u16x8 lo = *(const u16x8*)(xh + gbase + (size_t)p01 * 64);
      u16x8 hi = *(const u16x8*)(xh + gbase + (size_t)p01 * 64 + 8);
      #pragma unroll
      for (int j = 0; j < 8; ++j) { sacc[j] += w01 * b2f(lo[j]); sacc[8 + j] += w01 * b2f(hi[j]); }
    }
    {
      u16x8 lo = *(const u16x8*)(xh + gbase + (size_t)p10 * 64);
      u16x8 hi = *(const u16x8*)(xh + gbase + (size_t)p10 * 64 + 8);
      #pragma unroll
      for (int j = 0; j < 8; ++j) { sacc[j] += w10 * b2f(lo[j]); sacc[8 + j] += w10 * b2f(hi[j]); }
    }
    {
      u16x8 lo = *(const u16x8*)(xh + gbase + (size_t)p11 * 64);
      u16x8 hi = *(const u16x8*)(xh + gbase + (size_t)p11 * 64 + 8);
      #pragma unroll
      for (int j = 0; j < 8; ++j) { sacc[j] += w11 * b2f(lo[j]); sacc[8 + j] += w11 * b2f(hi[j]); }
    }
    u16x8 olo, ohi;
    #pragma unroll
    for (int j = 0; j < 8; ++j) { olo[j] = f2bf(sacc[j]); ohi[j] = f2bf(sacc[8 + j]); }
    unsigned short* sp = S + ((size_t)(kk * 4 + (g >> 2)) * MTOT + m) * 64 + (g & 3) * 16;
    *(u16x8*)sp = olo;
    *(u16x8*)(sp + 8) = ohi;
  }
}

// ========== Variant A: 8-wave (512-thr) GEMM, 128x128 tile, wave tile 64x32 ==========
// 2 waves/SIMD inside one block: ds_read/MFMA streams of co-resident waves overlap.
// Implicit im2col conv, K=2304, silu epilogue -> chunked bf16 planes.
__global__ __launch_bounds__(512, 1) void gemm8w_kernel(
    const unsigned short* __restrict__ A,   // chunked planes [c4][m][64]
    const unsigned short* __restrict__ W,   // [kk*4+c4][256 co][64]
    const float* __restrict__ bias,
    unsigned short* __restrict__ outp,      // chunked planes
    const unsigned short* __restrict__ zbuf) {
  constexpr int BM = 128, BN = 128, BK = 64;
  constexpr int NSTEP = 36;
  constexpr int BUFE = (BM + BN) * BK;            // 32 KB
  __shared__ unsigned short lds[2][BUFE];

  const int t = threadIdx.x, lane = t & 63, w = t >> 6;   // w: 0..7
  const int wm = w >> 2, wn = w & 3;
  const int m0 = blockIdx.x * BM, n0 = blockIdx.y * BN;

  // staging: chunk c = (i*8+w)*64 + lane (i=0..1); row = c>>3, swz col = (c&7)^(row&7)
  const unsigned short* baseA[2];
  const unsigned short* zsrcA[2];
  unsigned int vmaskA[2];
  #pragma unroll
  for (int i = 0; i < 2; ++i) {
    int c   = (i * 8 + w) * 64 + lane;
    int row = c >> 3;
    int ccl = (c & 7) ^ (row & 7);
    int m   = m0 + row;
    baseA[i] = A + (size_t)m * 64 + ccl * 8;
    zsrcA[i] = zbuf + ccl * 8;
    int y = (m >> 6) & 63, x = m & 63;
    unsigned int vm = 0;
    #pragma unroll
    for (int kk = 0; kk < 9; ++kk) {
      int dy = kk / 3 - 1, dx = kk % 3 - 1;
      if ((unsigned)(y + dy) < 64u && (unsigned)(x + dx) < 64u) vm |= (1u << kk);
    }
    vmaskA[i] = vm;
  }
  const unsigned short* baseB[2];
  #pragma unroll
  for (int j = 0; j < 2; ++j) {
    int c   = (j * 8 + w) * 64 + lane;
    int row = c >> 3;
    int ccl = (c & 7) ^ (row & 7);
    baseB[j] = W + (size_t)(n0 + row) * 64 + ccl * 8;
  }

  int offA[4][2], offB[2][2];
  #pragma unroll
  for (int mi = 0; mi < 4; ++mi) {
    int r = wm * 64 + mi * 16 + (lane & 15);
    #pragma unroll
    for (int kh = 0; kh < 2; ++kh) {
      int ccl = kh * 4 + (lane >> 4);
      offA[mi][kh] = r * 64 + ((ccl ^ (r & 7)) * 8);
    }
  }
  #pragma unroll
  for (int nj = 0; nj < 2; ++nj) {
    int r = wn * 32 + nj * 16 + (lane & 15);
    #pragma unroll
    for (int kh = 0; kh < 2; ++kh) {
      int ccl = kh * 4 + (lane >> 4);
      offB[nj][kh] = BM * BK + r * 64 + ((ccl ^ (r & 7)) * 8);
    }
  }

  f32x4 acc[4][2];
  #pragma unroll
  for (int mi = 0; mi < 4; ++mi)
    #pragma unroll
    for (int nj = 0; nj < 2; ++nj) acc[mi][nj] = (f32x4){0.f, 0.f, 0.f, 0.f};

  auto STAGE = [&](int sn, unsigned short* buf) {
    int kkn = sn >> 2;
    int q3  = kkn / 3;
    int dy = q3 - 1, dx = kkn - q3 * 3 - 1;
    const long aoff = (long)(sn & 3) * (MTOT * 64) + (long)(dy * 64 + dx) * 64;
    const long boff = (long)sn * (256 * 64);
    #pragma unroll
    for (int i = 0; i < 2; ++i) {
      const unsigned short* src = ((vmaskA[i] >> kkn) & 1u) ? baseA[i] + aoff : zsrcA[i];
      gload16(src, buf + (i * 8 + w) * 512);
    }
    #pragma unroll
    for (int j = 0; j < 2; ++j)
      gload16(baseB[j] + boff, buf + BM * BK + (j * 8 + w) * 512);
  };

  STAGE(0, lds[0]);

  for (int s = 0; s < NSTEP; ++s) {
    if (s + 1 < NSTEP) {
      STAGE(s + 1, lds[(s + 1) & 1]);
      asm volatile("s_waitcnt vmcnt(4)" ::: "memory");
    } else {
      asm volatile("s_waitcnt vmcnt(0)" ::: "memory");
    }
    __builtin_amdgcn_s_barrier();
    __builtin_amdgcn_sched_barrier(0);

    const unsigned short* cb = lds[s & 1];
    bf16x8 af[4][2], bfg[2][2];
    #pragma unroll
    for (int mi = 0; mi < 4; ++mi)
      #pragma unroll
      for (int kh = 0; kh < 2; ++kh)
        af[mi][kh] = *(const bf16x8*)&cb[offA[mi][kh]];
    #pragma unroll
    for (int nj = 0; nj < 2; ++nj)
      #pragma unroll
      for (int kh = 0; kh < 2; ++kh)
        bfg[nj][kh] = *(const bf16x8*)&cb[offB[nj][kh]];

    #pragma unroll
    for (int kh = 0; kh < 2; ++kh)
      #pragma unroll
      for (int mi = 0; mi < 4; ++mi)
        #pragma unroll
        for (int nj = 0; nj < 2; ++nj)
          acc[mi][nj] = __builtin_amdgcn_mfma_f32_16x16x32_bf16(af[mi][kh], bfg[nj][kh],
                                                                acc[mi][nj], 0, 0, 0);
    __builtin_amdgcn_sched_barrier(0);
    asm volatile("s_waitcnt lgkmcnt(0)" ::: "memory");
    __builtin_amdgcn_s_barrier();
  }

  const int gmBase = m0 + wm * 64 + (lane >> 4) * 4;
  const int gnBase = n0 + wn * 32 + (lane & 15);
  #pragma unroll
  for (int nj = 0; nj < 2; ++nj) {
    const int gn = gnBase + nj * 16;
    const float bv = bias[gn];
    #pragma unroll
    for (int mi = 0; mi < 4; ++mi) {
      #pragma unroll
      for (int r = 0; r < 4; ++r) {
        const int gm = gmBase + mi * 16 + r;
        float v = acc[mi][nj][r] + bv;
        float sv = v / (1.0f + __expf(-v));
        outp[((size_t)(gn >> 6) * MTOT + gm) * 64 + (gn & 63)] = f2bf(sv);
      }
    }
  }
}

// ========== Variant B: 4-wave split-K GEMM (18 steps/slice), atomic f32 accumulate ==========
// EPI: 1 = conv3 -> t3 f32 [m][432] (guard gn<432); 2 = deform -> f32 NCHW d_out.
template<int NPAD, int EPI, bool IMPLICIT>
__global__ __launch_bounds__(256, 2) void gemmsk_kernel(
    const unsigned short* __restrict__ A,
    const unsigned short* __restrict__ W,
    const float* __restrict__ bias,
    float* __restrict__ outp,
    const unsigned short* __restrict__ zbuf,
    int Nvalid) {
  constexpr int BM = 128, BN = 128, BK = 64;
  constexpr int NSTEP = 18;
  constexpr int BUFE = (BM + BN) * BK;
  __shared__ unsigned short lds[2][BUFE];

  const int t = threadIdx.x, lane = t & 63, w = t >> 6;
  const int wm = w >> 1, wn = w & 1;
  const int m0 = blockIdx.x * BM, n0 = blockIdx.y * BN;
  const int ks0 = blockIdx.z * NSTEP;

  const unsigned short* baseA[4];
  const unsigned short* zsrcA[4];
  unsigned int vmaskA[4];
  #pragma unroll
  for (int i = 0; i < 4; ++i) {
    int c   = (i * 4 + w) * 64 + lane;
    int row = c >> 3;
    int ccl = (c & 7) ^ (row & 7);
    int m   = m0 + row;
    baseA[i] = A + (size_t)m * 64 + ccl * 8;
    zsrcA[i] = zbuf + ccl * 8;
    if (IMPLICIT) {
      int y = (m >> 6) & 63, x = m & 63;
      unsigned int vm = 0;
      #pragma unroll
      for (int kk = 0; kk < 9; ++kk) {
        int dy = kk / 3 - 1, dx = kk % 3 - 1;
        if ((unsigned)(y + dy) < 64u && (unsigned)(x + dx) < 64u) vm |= (1u << kk);
      }
      vmaskA[i] = vm;
    } else {
      vmaskA[i] = 0;
    }
  }
  const unsigned short* baseB[4];
  #pragma unroll
  for (int j = 0; j < 4; ++j) {
    int c   = (j * 4 + w) * 64 + lane;
    int row = c >> 3;
    int ccl = (c & 7) ^ (row & 7);
    baseB[j] = W + (size_t)(n0 + row) * 64 + ccl * 8;
  }

  int offA[4][2], offB[4][2];
  #pragma unroll
  for (int mi = 0; mi < 4; ++mi) {
    int r = wm * 64 + mi * 16 + (lane & 15);
    #pragma unroll
    for (int kh = 0; kh < 2; ++kh) {
      int ccl = kh * 4 + (lane >> 4);
      offA[mi][kh] = r * 64 + ((ccl ^ (r & 7)) * 8);
    }
  }
  #pragma unroll
  for (int nj = 0; nj < 4; ++nj) {
    int r = wn * 64 + nj * 16 + (lane & 15);
    #pragma unroll
    for (int kh = 0; kh < 2; ++kh) {
      int ccl = kh * 4 + (lane >> 4);
      offB[nj][kh] = BM * BK + r * 64 + ((ccl ^ (r & 7)) * 8);
    }
  }

  f32x4 acc[4][4];
  #pragma unroll
  for (int mi = 0; mi < 4; ++mi)
    #pragma unroll
    for (int nj = 0; nj < 4; ++nj) acc[mi][nj] = (f32x4){0.f, 0.f, 0.f, 0.f};

  auto STAGE = [&](int sn, unsigned short* buf) {
    const int gs = ks0 + sn;
    const long boff = (long)gs * (NPAD * 64);
    if (IMPLICIT) {
      int kkn = gs >> 2;
      int q3  = kkn / 3;
      int dy = q3 - 1, dx = kkn - q3 * 3 - 1;
      const long aoff = (long)(gs & 3) * (MTOT * 64) + (long)(dy * 64 + dx) * 64;
      #pragma unroll
      for (int i = 0; i < 4; ++i) {
        const unsigned short* src = ((vmaskA[i] >> kkn) & 1u) ? baseA[i] + aoff : zsrcA[i];
        gload16(src, buf + (i * 4 + w) * 512);
      }
    } else {
      const long aoff = (long)gs * (MTOT * 64);
      #pragma unroll
      for (int i = 0; i < 4; ++i)
        gload16(baseA[i] + aoff, buf + (i * 4 + w) * 512);
    }
    #pragma unroll
    for (int j = 0; j < 4; ++j)
      gload16(baseB[j] + boff, buf + BM * BK + (j * 4 + w) * 512);
  };

  STAGE(0, lds[0]);

  for (int s = 0; s < NSTEP; ++s) {
    if (s + 1 < NSTEP) {
      STAGE(s + 1, lds[(s + 1) & 1]);
      asm volatile("s_waitcnt vmcnt(8)" ::: "memory");
    } else {
      asm volatile("s_waitcnt vmcnt(0)" ::: "memory");
    }
    __builtin_amdgcn_s_barrier();
    __builtin_amdgcn_sched_barrier(0);

    const unsigned short* cb = lds[s & 1];
    bf16x8 af[4][2], bfg[4][2];
    #pragma unroll
    for (int mi = 0; mi < 4; ++mi)
      #pragma unroll
      for (int kh = 0; kh < 2; ++kh)
        af[mi][kh] = *(const bf16x8*)&cb[offA[mi][kh]];
    #pragma unroll
    for (int nj = 0; nj < 4; ++nj)
      #pragma unroll
      for (int kh = 0; kh < 2; ++kh)
        bfg[nj][kh] = *(const bf16x8*)&cb[offB[nj][kh]];

    #pragma unroll
    for (int kh = 0; kh < 2; ++kh)
      #pragma unroll
      for (int mi = 0; mi < 4; ++mi)
        #pragma unroll
        for (int nj = 0; nj < 4; ++nj)
          acc[mi][nj] = __builtin_amdgcn_mfma_f32_16x16x32_bf16(af[mi][kh], bfg[nj][kh],
                                                                acc[mi][nj], 0, 0, 0);
    __builtin_amdgcn_sched_barrier(0);
    asm volatile("s_waitcnt lgkmcnt(0)" ::: "memory");
    __builtin_amdgcn_s_barrier();
  }

  const int gmBase = m0 + wm * 64 + (lane >> 4) * 4;
  const int gnBase = n0 + wn * 64 + (lane & 15);
  const bool addb = (ks0 == 0);
  #pragma unroll
  for (int nj = 0; nj < 4; ++nj) {
    const int gn = gnBase + nj * 16;
    const float bv = (addb && gn < Nvalid) ? bias[gn] : 0.f;
    #pragma unroll
    for (int mi = 0; mi < 4; ++mi) {
      #pragma unroll
      for (int r = 0; r < 4; ++r) {
        const int gm = gmBase + mi * 16 + r;
        float v = acc[mi][nj][r] + bv;
        if (EPI == 1) {
          if (gn < Nvalid) unsafeAtomicAdd(&outp[(size_t)gm * 432 + gn], v);
        } else {
          unsafeAtomicAdd(&outp[((size_t)(gm >> 12) * 256 + gn) * 4096 + (gm & 4095)], v);
        }
      }
    }
  }
}

extern "C" void kernel_launch(void* const* d_in, const int* in_sizes, int n_in,
                              void* d_out, int out_size, void* d_ws, size_t ws_size,
                              hipStream_t stream) {
  const float* x      = (const float*)d_in[0];
  const float* offeat = (const float*)d_in[1];
  const float* weight = (const float*)d_in[2];
  const float* bias   = (const float*)d_in[3];
  const float* w1     = (const float*)d_in[4];
  const float* b1     = (const float*)d_in[5];
  const float* w2     = (const float*)d_in[6];
  const float* b2     = (const float*)d_in[7];
  const float* w3     = (const float*)d_in[8];
  const float* b3     = (const float*)d_in[9];
  float* out = (float*)d_out;

  char* ws = (char*)d_ws;
  // persistent region
  unsigned short* xh  = (unsigned short*)(ws + 0);            //  8,388,608 B (4 planes)
  float*          t3  = (float*)(ws + 8388608);               // 28,311,552 B
  unsigned short* Wd  = (unsigned short*)(ws + 36700160);     //  1,179,648 B
  unsigned short* zb  = (unsigned short*)(ws + 37879808);     //        256 B
  unsigned short* S   = (unsigned short*)(ws + 37880064);     // 75,497,472 B (36 planes)
  // overlay region inside S's span (all dead before sampler writes S)
  unsigned short* fh  = (unsigned short*)(ws + 37880064);     //  8,388,608 B
  unsigned short* t1  = (unsigned short*)(ws + 46268672);     //  8,388,608 B
  unsigned short* t2  = (unsigned short*)(ws + 54657280);     //  8,388,608 B
  unsigned short* W1p = (unsigned short*)(ws + 63045888);     //  1,179,648 B
  unsigned short* W2p = (unsigned short*)(ws + 64225536);     //  1,179,648 B
  unsigned short* W3p = (unsigned short*)(ws + 65405184);     //  2,359,296 B (NPAD 512)

  hipMemsetAsync(zb, 0, 256, stream);

  // layout conversions
  nhwc_kernel<<<dim3(64, 4), 256, 0, stream>>>(x, xh);
  nhwc_kernel<<<dim3(64, 4), 256, 0, stream>>>(offeat, fh);
  wprep_kernel<<<dim3(36, 64), 256, 0, stream>>>(w1, W1p, 256, 256);
  wprep_kernel<<<dim3(36, 64), 256, 0, stream>>>(w2, W2p, 256, 256);
  wprep_kernel<<<dim3(36, 128), 256, 0, stream>>>(w3, W3p, 512, 432);
  wprep_kernel<<<dim3(36, 64), 256, 0, stream>>>(weight, Wd, 256, 256);

  // conv1 (silu) -> t1, conv2 (silu) -> t2   [Variant A: 8-wave blocks]
  gemm8w_kernel<<<dim3(128, 2), 512, 0, stream>>>(fh, W1p, b1, t1, zb);
  gemm8w_kernel<<<dim3(128, 2), 512, 0, stream>>>(t1, W2p, b2, t2, zb);

  // conv3 -> t3 (f32, atomic accumulate)   [Variant B: split-K=2]
  hipMemsetAsync(t3, 0, 28311552, stream);
  gemmsk_kernel<512, 1, true><<<dim3(128, 4, 2), 256, 0, stream>>>(t2, W3p, b3, t3, zb, 432);

  // bilinear sampling -> S planes
  sampler_kernel<<<dim3(1024), 256, 0, stream>>>(t3, xh, S);

  // deform GEMM -> out (f32 NCHW, atomic accumulate)   [Variant B: split-K=2]
  hipMemsetAsync(out, 0, (size_t)out_size * 4, stream);
  gemmsk_kernel<256, 2, false><<<dim3(128, 2, 2), 256, 0, stream>>>(S, Wd, bias, out, zb, 256);
}

// Round 14
// 196.308 us; speedup vs baseline: 1.6692x; 1.6692x over previous
//
#include <hip/hip_runtime.h>
#include <math.h>

typedef __attribute__((ext_vector_type(8))) short  bf16x8;
typedef __attribute__((ext_vector_type(8))) unsigned short u16x8;
typedef __attribute__((ext_vector_type(4))) float  f32x4;

#define MTOT 16384   // B*H*W

__device__ __forceinline__ float b2f(unsigned short h) {
  return __uint_as_float(((unsigned int)h) << 16);
}
__device__ __forceinline__ unsigned short f2bf(float f) {
  unsigned int u = __float_as_uint(f);
  unsigned int r = (u + 0x7fffu + ((u >> 16) & 1u)) >> 16;
  return (unsigned short)r;
}
__device__ __forceinline__ void gload16(const unsigned short* g, unsigned short* l) {
  __builtin_amdgcn_global_load_lds(
      (const __attribute__((address_space(1))) void*)g,
      (__attribute__((address_space(3))) void*)l, 16, 0, 0);
}

// ------- NCHW fp32 -> chunked bf16 planes  out[c4][m][64]  (m = b*4096 + y*64 + x) -------
__global__ __launch_bounds__(256) void nhwc_kernel(const float* __restrict__ in,
                                                   unsigned short* __restrict__ out) {
  const int y = blockIdx.x, b = blockIdx.y;
  const int t = threadIdx.x;
  __shared__ float lds[64 * 65];
  for (int c0 = 0; c0 < 256; c0 += 64) {
    #pragma unroll
    for (int i = 0; i < 16; ++i) {
      int cl = i * 4 + (t >> 6);
      int xx = t & 63;
      lds[cl * 65 + xx] = in[(((size_t)b * 256 + c0 + cl) * 64 + y) * 64 + xx];
    }
    __syncthreads();
    const int plane = c0 >> 6;
    #pragma unroll
    for (int i = 0; i < 16; ++i) {
      int xx = i * 4 + (t >> 6);
      int cl = t & 63;
      int m  = (b << 12) + (y << 6) + xx;
      out[((size_t)plane * MTOT + m) * 64 + cl] = f2bf(lds[cl * 65 + xx]);
    }
    __syncthreads();
  }
}

// ------- weight reorder: w[co][ci][kk] fp32 -> Wp[(kk*4+c4)*NPAD + co][64ci] bf16 -------
__global__ __launch_bounds__(256) void wprep_kernel(const float* __restrict__ w,
                                                    unsigned short* __restrict__ Wp,
                                                    int NPAD, int COUT_valid) {
  const int kkc4 = blockIdx.x;             // 0..35
  const int kk = kkc4 >> 2, c4 = kkc4 & 3;
  const int co = blockIdx.y * 4 + (threadIdx.x >> 6);
  const int c16 = threadIdx.x & 63;
  float v = (co < COUT_valid) ? w[((size_t)co * 256 + c4 * 64 + c16) * 9 + kk] : 0.0f;
  Wp[((size_t)kkc4 * NPAD + co) * 64 + c16] = f2bf(v);
}

// ------- bilinear sampler: t3 ([m][432] f32) + xh (chunked) -> S[s-plane][m][64] bf16 -------
__global__ __launch_bounds__(256) void sampler_kernel(const float* __restrict__ t3,
                                                      const unsigned short* __restrict__ xh,
                                                      unsigned short* __restrict__ S) {
  const int t = threadIdx.x;
  const int g = t & 15;
  const int m = blockIdx.x * 16 + (t >> 4);
  const int b = m >> 12, pix = m & 4095, y = pix >> 6, x = pix & 63;
  const float* off = t3 + (size_t)m * 432;
  const size_t gbase = ((size_t)(g >> 2) * MTOT + ((size_t)b << 12)) * 64 + (g & 3) * 16;

  #pragma unroll
  for (int kk = 0; kk < 9; ++kk) {
    const int ki = kk / 3, kj = kk % 3;
    float dyv = off[2 * (g * 9 + kk)];
    float dxv = off[2 * (g * 9 + kk) + 1];
    float ml  = off[288 + g * 9 + kk];
    float mk  = 1.0f / (1.0f + __expf(-ml));
    float ysf = (float)(y - 1 + ki) + dyv;
    float xsf = (float)(x - 1 + kj) + dxv;
    float y0f = floorf(ysf), x0f = floorf(xsf);
    float wy = ysf - y0f, wx = xsf - x0f;
    int yi0 = (int)y0f, xi0 = (int)x0f;
    int yi1 = yi0 + 1, xi1 = xi0 + 1;
    bool vy0 = (yi0 >= 0) && (yi0 < 64), vy1 = (yi1 >= 0) && (yi1 < 64);
    bool vx0 = (xi0 >= 0) && (xi0 < 64), vx1 = (xi1 >= 0) && (xi1 < 64);
    int yc0 = min(max(yi0, 0), 63), yc1 = min(max(yi1, 0), 63);
    int xc0 = min(max(xi0, 0), 63), xc1 = min(max(xi1, 0), 63);
    float w00 = (vy0 && vx0) ? (1.f - wy) * (1.f - wx) * mk : 0.f;
    float w01 = (vy0 && vx1) ? (1.f - wy) * wx * mk : 0.f;
    float w10 = (vy1 && vx0) ? wy * (1.f - wx) * mk : 0.f;
    float w11 = (vy1 && vx1) ? wy * wx * mk : 0.f;

    float sacc[16];
    #pragma unroll
    for (int c = 0; c < 16; ++c) sacc[c] = 0.f;

    const int p00 = yc0 * 64 + xc0, p01 = yc0 * 64 + xc1;
    const int p10 = yc1 * 64 + xc0, p11 = yc1 * 64 + xc1;
    {
      u16x8 lo = *(const u16x8*)(xh + gbase + (size_t)p00 * 64);
      u16x8 hi = *(const u16x8*)(xh + gbase + (size_t)p00 * 64 + 8);
      #pragma unroll
      for (int j = 0; j < 8; ++j) { sacc[j] += w00 * b2f(lo[j]); sacc[8 + j] += w00 * b2f(hi[j]); }
    }
    {
      u16x8 lo = *(const u16x8*)(xh + gbase + (size_t)p01 * 64);
      u16x8 hi = *(const u16x8*)(xh + gbase + (size_t)p01 * 64 + 8);
      #pragma unroll
      for (int j = 0; j < 8; ++j) { sacc[j] += w01 * b2f(lo[j]); sacc[8 + j] += w01 * b2f(hi[j]); }
    }
    {
      u16x8 lo = *(const u16x8*)(xh + gbase + (size_t)p10 * 64);
      u16x8 hi = *(const u16x8*)(xh + gbase + (size_t)p10 * 64 + 8);
      #pragma unroll
      for (int j = 0; j < 8; ++j) { sacc[j] += w10 * b2f(lo[j]); sacc[8 + j] += w10 * b2f(hi[j]); }
    }
    {
      u16x8 lo = *(const u16x8*)(xh + gbase + (size_t)p11 * 64);
      u16x8 hi = *(const u16x8*)(xh + gbase + (size_t)p11 * 64 + 8);
      #pragma unroll
      for (int j = 0; j < 8; ++j) { sacc[j] += w11 * b2f(lo[j]); sacc[8 + j] += w11 * b2f(hi[j]); }
    }
    u16x8 olo, ohi;
    #pragma unroll
    for (int j = 0; j < 8; ++j) { olo[j] = f2bf(sacc[j]); ohi[j] = f2bf(sacc[8 + j]); }
    unsigned short* sp = S + ((size_t)(kk * 4 + (g >> 2)) * MTOT + m) * 64 + (g & 3) * 16;
    *(u16x8*)sp = olo;
    *(u16x8*)(sp + 8) = ohi;
  }
}

// ========== 8-wave (512-thr) MFMA GEMM, 128x128 tile, wave tile 64x32 ==========
// C[16384][N] = A x W^T over K=2304 (36 planes of 64).  Double-buffered LDS (64 KB),
// counted vmcnt(4). 2 waves/SIMD min (4 with 2 blocks/CU) -> TLP hides step latency.
// EPI: 0 = silu -> bf16 chunked planes; 1 = f32 [m][432]+bias (guard gn<Nvalid); 2 = f32 NCHW.
template<int NPAD, int EPI, bool IMPLICIT>
__global__ __launch_bounds__(512, 1) void gemm8_kernel(
    const unsigned short* __restrict__ A,   // chunked planes [c4][m][64] or S planes
    const unsigned short* __restrict__ W,   // [kk*4+c4][NPAD co][64]
    const float* __restrict__ bias,
    void* __restrict__ outp,
    const unsigned short* __restrict__ zbuf,
    int Nvalid) {
  constexpr int BM = 128, BN = 128, BK = 64;
  constexpr int NSTEP = 36;
  constexpr int BUFE = (BM + BN) * BK;            // 32 KB
  __shared__ unsigned short lds[2][BUFE];

  const int t = threadIdx.x, lane = t & 63, w = t >> 6;   // w: 0..7
  const int wm = w >> 2, wn = w & 3;
  const int m0 = blockIdx.x * BM, n0 = blockIdx.y * BN;

  // staging: chunk c = (i*8+w)*64 + lane (i=0..1); row = c>>3, swz col = (c&7)^(row&7)
  const unsigned short* baseA[2];
  const unsigned short* zsrcA[2];
  unsigned int vmaskA[2];
  #pragma unroll
  for (int i = 0; i < 2; ++i) {
    int c   = (i * 8 + w) * 64 + lane;
    int row = c >> 3;
    int ccl = (c & 7) ^ (row & 7);
    int m   = m0 + row;
    baseA[i] = A + (size_t)m * 64 + ccl * 8;
    zsrcA[i] = zbuf + ccl * 8;
    if (IMPLICIT) {
      int y = (m >> 6) & 63, x = m & 63;
      unsigned int vm = 0;
      #pragma unroll
      for (int kk = 0; kk < 9; ++kk) {
        int dy = kk / 3 - 1, dx = kk % 3 - 1;
        if ((unsigned)(y + dy) < 64u && (unsigned)(x + dx) < 64u) vm |= (1u << kk);
      }
      vmaskA[i] = vm;
    } else {
      vmaskA[i] = 0;
    }
  }
  const unsigned short* baseB[2];
  #pragma unroll
  for (int j = 0; j < 2; ++j) {
    int c   = (j * 8 + w) * 64 + lane;
    int row = c >> 3;
    int ccl = (c & 7) ^ (row & 7);
    baseB[j] = W + (size_t)(n0 + row) * 64 + ccl * 8;
  }

  int offA[4][2], offB[2][2];
  #pragma unroll
  for (int mi = 0; mi < 4; ++mi) {
    int r = wm * 64 + mi * 16 + (lane & 15);
    #pragma unroll
    for (int kh = 0; kh < 2; ++kh) {
      int ccl = kh * 4 + (lane >> 4);
      offA[mi][kh] = r * 64 + ((ccl ^ (r & 7)) * 8);
    }
  }
  #pragma unroll
  for (int nj = 0; nj < 2; ++nj) {
    int r = wn * 32 + nj * 16 + (lane & 15);
    #pragma unroll
    for (int kh = 0; kh < 2; ++kh) {
      int ccl = kh * 4 + (lane >> 4);
      offB[nj][kh] = BM * BK + r * 64 + ((ccl ^ (r & 7)) * 8);
    }
  }

  f32x4 acc[4][2];
  #pragma unroll
  for (int mi = 0; mi < 4; ++mi)
    #pragma unroll
    for (int nj = 0; nj < 2; ++nj) acc[mi][nj] = (f32x4){0.f, 0.f, 0.f, 0.f};

  auto STAGE = [&](int sn, unsigned short* buf) {
    const long boff = (long)sn * (NPAD * 64);
    if (IMPLICIT) {
      int kkn = sn >> 2;
      int q3  = kkn / 3;
      int dy = q3 - 1, dx = kkn - q3 * 3 - 1;
      const long aoff = (long)(sn & 3) * (MTOT * 64) + (long)(dy * 64 + dx) * 64;
      #pragma unroll
      for (int i = 0; i < 2; ++i) {
        const unsigned short* src = ((vmaskA[i] >> kkn) & 1u) ? baseA[i] + aoff : zsrcA[i];
        gload16(src, buf + (i * 8 + w) * 512);
      }
    } else {
      const long aoff = (long)sn * (MTOT * 64);
      #pragma unroll
      for (int i = 0; i < 2; ++i)
        gload16(baseA[i] + aoff, buf + (i * 8 + w) * 512);
    }
    #pragma unroll
    for (int j = 0; j < 2; ++j)
      gload16(baseB[j] + boff, buf + BM * BK + (j * 8 + w) * 512);
  };

  STAGE(0, lds[0]);

  for (int s = 0; s < NSTEP; ++s) {
    if (s + 1 < NSTEP) {
      STAGE(s + 1, lds[(s + 1) & 1]);                  // 4 loads stay in flight across barrier
      asm volatile("s_waitcnt vmcnt(4)" ::: "memory"); // wait only current buffer's 4
    } else {
      asm volatile("s_waitcnt vmcnt(0)" ::: "memory");
    }
    __builtin_amdgcn_s_barrier();
    __builtin_amdgcn_sched_barrier(0);

    const unsigned short* cb = lds[s & 1];
    bf16x8 af[4][2], bfg[2][2];
    #pragma unroll
    for (int mi = 0; mi < 4; ++mi)
      #pragma unroll
      for (int kh = 0; kh < 2; ++kh)
        af[mi][kh] = *(const bf16x8*)&cb[offA[mi][kh]];
    #pragma unroll
    for (int nj = 0; nj < 2; ++nj)
      #pragma unroll
      for (int kh = 0; kh < 2; ++kh)
        bfg[nj][kh] = *(const bf16x8*)&cb[offB[nj][kh]];

    #pragma unroll
    for (int kh = 0; kh < 2; ++kh)
      #pragma unroll
      for (int mi = 0; mi < 4; ++mi)
        #pragma unroll
        for (int nj = 0; nj < 2; ++nj)
          acc[mi][nj] = __builtin_amdgcn_mfma_f32_16x16x32_bf16(af[mi][kh], bfg[nj][kh],
                                                                acc[mi][nj], 0, 0, 0);
    __builtin_amdgcn_sched_barrier(0);
    asm volatile("s_waitcnt lgkmcnt(0)" ::: "memory");
    __builtin_amdgcn_s_barrier();
  }

  // epilogue: C/D layout col = lane&15, row = (lane>>4)*4 + reg
  const int gmBase = m0 + wm * 64 + (lane >> 4) * 4;
  const int gnBase = n0 + wn * 32 + (lane & 15);
  #pragma unroll
  for (int nj = 0; nj < 2; ++nj) {
    const int gn = gnBase + nj * 16;
    const float bv = (gn < Nvalid) ? bias[gn] : 0.f;
    #pragma unroll
    for (int mi = 0; mi < 4; ++mi) {
      #pragma unroll
      for (int r = 0; r < 4; ++r) {
        const int gm = gmBase + mi * 16 + r;
        float v = acc[mi][nj][r] + bv;
        if (EPI == 0) {
          float sv = v / (1.0f + __expf(-v));
          ((unsigned short*)outp)[((size_t)(gn >> 6) * MTOT + gm) * 64 + (gn & 63)] = f2bf(sv);
        } else if (EPI == 1) {
          if (gn < Nvalid) ((float*)outp)[(size_t)gm * 432 + gn] = v;
        } else {
          ((float*)outp)[((size_t)(gm >> 12) * 256 + gn) * 4096 + (gm & 4095)] = v;
        }
      }
    }
  }
}

extern "C" void kernel_launch(void* const* d_in, const int* in_sizes, int n_in,
                              void* d_out, int out_size, void* d_ws, size_t ws_size,
                              hipStream_t stream) {
  const float* x      = (const float*)d_in[0];
  const float* offeat = (const float*)d_in[1];
  const float* weight = (const float*)d_in[2];
  const float* bias   = (const float*)d_in[3];
  const float* w1     = (const float*)d_in[4];
  const float* b1     = (const float*)d_in[5];
  const float* w2     = (const float*)d_in[6];
  const float* b2     = (const float*)d_in[7];
  const float* w3     = (const float*)d_in[8];
  const float* b3     = (const float*)d_in[9];
  float* out = (float*)d_out;

  char* ws = (char*)d_ws;
  // persistent region
  unsigned short* xh  = (unsigned short*)(ws + 0);            //  8,388,608 B (4 planes)
  float*          t3  = (float*)(ws + 8388608);               // 28,311,552 B
  unsigned short* Wd  = (unsigned short*)(ws + 36700160);     //  1,179,648 B
  unsigned short* zb  = (unsigned short*)(ws + 37879808);     //        256 B
  unsigned short* S   = (unsigned short*)(ws + 37880064);     // 75,497,472 B (36 planes)
  // overlay region inside S's span (all dead before sampler writes S)
  unsigned short* fh  = (unsigned short*)(ws + 37880064);     //  8,388,608 B
  unsigned short* t1  = (unsigned short*)(ws + 46268672);     //  8,388,608 B
  unsigned short* t2  = (unsigned short*)(ws + 54657280);     //  8,388,608 B
  unsigned short* W1p = (unsigned short*)(ws + 63045888);     //  1,179,648 B
  unsigned short* W2p = (unsigned short*)(ws + 64225536);     //  1,179,648 B
  unsigned short* W3p = (unsigned short*)(ws + 65405184);     //  2,359,296 B (NPAD 512)

  hipMemsetAsync(zb, 0, 256, stream);

  // layout conversions
  nhwc_kernel<<<dim3(64, 4), 256, 0, stream>>>(x, xh);
  nhwc_kernel<<<dim3(64, 4), 256, 0, stream>>>(offeat, fh);
  wprep_kernel<<<dim3(36, 64), 256, 0, stream>>>(w1, W1p, 256, 256);
  wprep_kernel<<<dim3(36, 64), 256, 0, stream>>>(w2, W2p, 256, 256);
  wprep_kernel<<<dim3(36, 128), 256, 0, stream>>>(w3, W3p, 512, 432);
  wprep_kernel<<<dim3(36, 64), 256, 0, stream>>>(weight, Wd, 256, 256);

  // conv1 (silu) -> t1, conv2 (silu) -> t2  [8-wave, 1 block/CU]
  gemm8_kernel<256, 0, true><<<dim3(128, 2), 512, 0, stream>>>(fh, W1p, b1, t1, zb, 256);
  gemm8_kernel<256, 0, true><<<dim3(128, 2), 512, 0, stream>>>(t1, W2p, b2, t2, zb, 256);

  // conv3 -> t3 (f32 + bias, direct stores)  [8-wave, 2 blocks/CU]
  gemm8_kernel<512, 1, true><<<dim3(128, 4), 512, 0, stream>>>(t2, W3p, b3, t3, zb, 432);

  // bilinear sampling -> S planes
  sampler_kernel<<<dim3(1024), 256, 0, stream>>>(t3, xh, S);

  // deform GEMM -> out (f32 NCHW, direct stores)  [8-wave]
  gemm8_kernel<256, 2, false><<<dim3(128, 2), 512, 0, stream>>>(S, Wd, bias, out, zb, 256);
}